// Round 10
// baseline (138.591 us; speedup 1.0000x reference)
//
#include <hip/hip_runtime.h>
#include <hip/hip_bf16.h>

// Problem constants: B=8, C=256, Ci=128, H=W=64, N=4096, M=1024
#define NB 8
#define NC 256
#define NCI 128
#define NSP 4096
#define NM 1024

typedef float f32x4 __attribute__((ext_vector_type(4)));
typedef float f32x16 __attribute__((ext_vector_type(16)));
typedef short s16x8 __attribute__((ext_vector_type(8)));
typedef unsigned short u16;

// Workspace layout (byte offsets, total < 64 MB)
#define OFF_XH  (0ull)              // xh bf16 [B][N][C]  16 MB (dead after proj)
#define OFF_XL  (16777216ull)       // xl bf16 [B][N][C]  16 MB (dead after proj)
#define OFF_THT (33554432ull)       // thT bf16 [B][N][Ci] 8 MB (dead after attn)
#define OFF_PHT (41943040ull)       // phT bf16 [B][M][Ci] 2 MB
#define OFF_GP  (44040192ull)       // gp  bf16 [B][Ci][M] 2 MB
#define OFF_YH  (46137344ull)       // yh  bf16 [B][N][Ci] 8 MB
#define OFF_YL  (54525952ull)       // yl  bf16 [B][N][Ci] 8 MB
#define OFF_WY  (0ull)              // wy f32 [B][C][N] 32 MB (overlays XH+XL, dead)
// NOTE: wy MUST be f32. BN divides by per-channel sigma(wy) which is tiny vs |mean(wy)|
// (attention output nearly constant over n) -> bf16 wy quantization (|mean|*2^-9/sigma)
// lands ~0.25 on the output. Measured twice (rounds 5, 8).
#define OFF_WBH (62914560ull)       // wb hi bf16 [384][256] 192 KB
#define OFF_WBL (63111168ull)       // wb lo
#define OFF_WWH (63307776ull)       // wwb hi bf16 [256][128] 64 KB
#define OFF_WWL (63373312ull)       // wwb lo
#define OFF_S   (63438848ull)       // s1[256], s2[256] f32

#define GLL(src, dst) __builtin_amdgcn_global_load_lds( \
    (const __attribute__((address_space(1))) unsigned*)(src), \
    (__attribute__((address_space(3))) unsigned*)(dst), 16, 0, 0)

__device__ __forceinline__ u16 f2bf(float f) {
  union { __hip_bfloat16 h; u16 u; } v;
  v.h = __float2bfloat16(f);
  return v.u;
}
__device__ __forceinline__ float bf2f(u16 u) {
  union { unsigned u; float f; } v;
  v.u = (unsigned)u << 16;
  return v.f;
}
__device__ __forceinline__ u16 bfmax4(u16 a, u16 b, u16 c, u16 d) {
  float v = fmaxf(fmaxf(bf2f(a), bf2f(b)), fmaxf(bf2f(c), bf2f(d)));
  return f2bf(v);
}
__device__ __forceinline__ unsigned cvtpk(float lo, float hi) {
  unsigned r;
  asm volatile("v_cvt_pk_bf16_f32 %0, %1, %2" : "=v"(r) : "v"(lo), "v"(hi));
  return r;
}

__global__ void zero_stats(float* s) { s[threadIdx.x] = 0.f; }

// ---- weights -> bf16 hi/lo (wb stacked: rows 0-127 g, 128-255 theta, 256-383 phi) --
__global__ __launch_bounds__(256) void wcvt(
    const float* __restrict__ wg, const float* __restrict__ wth,
    const float* __restrict__ wph, const float* __restrict__ ww,
    u16* __restrict__ wbh, u16* __restrict__ wbl,
    u16* __restrict__ wwh, u16* __restrict__ wwl)
{
  int idx = blockIdx.x * 256 + threadIdx.x;
  if (idx < 384 * 256) {
    int row = idx >> 8, k = idx & 255;
    float v = row < 128 ? wg[row * 256 + k]
            : row < 256 ? wth[(row - 128) * 256 + k]
                        : wph[(row - 256) * 256 + k];
    u16 h = f2bf(v);
    wbh[idx] = h;
    wbl[idx] = f2bf(v - bf2f(h));
  } else {
    int j = idx - 384 * 256;
    float v = ww[j];
    u16 h = f2bf(v);
    wwh[j] = h;
    wwl[j] = f2bf(v - bf2f(h));
  }
}

// ---- x [B][C][N] f32 -> xh/xl [B][N][C] bf16 hi/lo (transpose + split) -------------
__global__ __launch_bounds__(256) void xt_cvt(const float* __restrict__ x,
                                              u16* __restrict__ xh, u16* __restrict__ xl)
{
  __shared__ float t[64 * 68];
  const int n0 = blockIdx.x << 6, c0 = blockIdx.y << 6, b = blockIdx.z;
  const int tid = threadIdx.x;
  const int cl = tid >> 4, n4 = (tid & 15) << 2;
#pragma unroll
  for (int it = 0; it < 4; ++it) {
    int c = it * 16 + cl;
    float4 v = *(const float4*)&x[((size_t)(b * NC + c0 + c)) * NSP + n0 + n4];
    *(float4*)&t[c * 68 + n4] = v;
  }
  __syncthreads();
#pragma unroll
  for (int it = 0; it < 2; ++it) {
    int task = it * 256 + tid;
    int n = task >> 3, cc = (task & 7) << 3;
    u16 oh[8], ol[8];
#pragma unroll
    for (int i = 0; i < 8; ++i) {
      float v = t[(cc + i) * 68 + n];
      oh[i] = f2bf(v);
      ol[i] = f2bf(v - bf2f(oh[i]));
    }
    size_t dst = ((size_t)(b * NSP + n0 + n)) * NC + c0 + cc;
    *(s16x8*)&xh[dst] = *(s16x8*)oh;
    *(s16x8*)&xl[dst] = *(s16x8*)ol;
  }
}

// ---- fused projection: all 384 channels, 3-pass split MFMA, bias+pool+layouts ------
__global__ __launch_bounds__(512, 1) void proj_fused(
    const u16* __restrict__ xh, const u16* __restrict__ xl,
    const u16* __restrict__ wbh, const u16* __restrict__ wbl,
    const float* __restrict__ bg, const float* __restrict__ bth,
    const float* __restrict__ bph,
    u16* __restrict__ thT, u16* __restrict__ phT, u16* __restrict__ gp)
{
  __shared__ char smem[132608];
  u16* xsh = (u16*)smem;                 // [128 n][64 k]  16 KB swizzled
  u16* xsl = (u16*)(smem + 16384);       // [128 n][64 k]  16 KB
  u16* wsh = (u16*)(smem + 32768);       // [384 o][64 k]  48 KB
  u16* wsl = (u16*)(smem + 81920);       // [384 o][64 k]  48 KB
  u16* outl = (u16*)smem;                // epilogue [384][137] bf16 overlay
  float* bias = (float*)(smem + 131072); // 384 f32

  const int b = blockIdx.y, h2 = blockIdx.x;
  const int n0 = h2 << 7;
  const int tid = threadIdx.x;
  const int wave = tid >> 6, lane = tid & 63;
  const int lo16 = lane & 15, hi4 = lane >> 4;
  const int wr = wave >> 1, wc = wave & 1;
  const int obase = wr * 96, nbase = wc * 64;

  if (tid < 384)
    bias[tid] = tid < 128 ? bg[tid] : tid < 256 ? bth[tid - 128] : bph[tid - 256];

  f32x4 acc[6][4];
#pragma unroll
  for (int i = 0; i < 6; ++i)
#pragma unroll
    for (int j = 0; j < 4; ++j) acc[i][j] = (f32x4){0.f, 0.f, 0.f, 0.f};

  for (int step = 0; step < 4; ++step) {
    __syncthreads();
#pragma unroll
    for (int i = 0; i < 2; ++i) {
      int ci = i * 512 + tid;
      int n = ci >> 3, slot = ci & 7;
      size_t rowb = ((size_t)(b * NSP + n0 + n)) * 512 + step * 128 + ((slot ^ (n & 7)) << 4);
      GLL((const char*)xh + rowb, (char*)xsh + (size_t)(i * 512 + (tid & ~63)) * 16);
      GLL((const char*)xl + rowb, (char*)xsl + (size_t)(i * 512 + (tid & ~63)) * 16);
    }
#pragma unroll
    for (int i = 0; i < 6; ++i) {
      int ci = i * 512 + tid;
      int o = ci >> 3, slot = ci & 7;
      size_t rowb = (size_t)o * 512 + step * 128 + ((slot ^ (o & 7)) << 4);
      GLL((const char*)wbh + rowb, (char*)wsh + (size_t)(i * 512 + (tid & ~63)) * 16);
      GLL((const char*)wbl + rowb, (char*)wsl + (size_t)(i * 512 + (tid & ~63)) * 16);
    }
    __syncthreads();

#pragma unroll
    for (int kc = 0; kc < 2; ++kc) {
      const int sl = kc * 4 + hi4;
      s16x8 bfh[4], bfl[4];
#pragma unroll
      for (int fn = 0; fn < 4; ++fn) {
        int n = nbase + fn * 16 + lo16;
        int off = (int)n * 128 + ((sl ^ (n & 7)) << 4);
        bfh[fn] = *(const s16x8*)((const char*)xsh + off);
        bfl[fn] = *(const s16x8*)((const char*)xsl + off);
      }
      __builtin_amdgcn_s_setprio(1);
#pragma unroll
      for (int fo = 0; fo < 6; ++fo) {
        int o = obase + fo * 16 + lo16;
        int off = (int)o * 128 + ((sl ^ (o & 7)) << 4);
        s16x8 afh = *(const s16x8*)((const char*)wsh + off);
        s16x8 afl = *(const s16x8*)((const char*)wsl + off);
#pragma unroll
        for (int fn = 0; fn < 4; ++fn) {
          acc[fo][fn] = __builtin_amdgcn_mfma_f32_16x16x32_bf16(afh, bfh[fn], acc[fo][fn], 0, 0, 0);
          acc[fo][fn] = __builtin_amdgcn_mfma_f32_16x16x32_bf16(afh, bfl[fn], acc[fo][fn], 0, 0, 0);
          acc[fo][fn] = __builtin_amdgcn_mfma_f32_16x16x32_bf16(afl, bfh[fn], acc[fo][fn], 0, 0, 0);
        }
      }
      __builtin_amdgcn_s_setprio(0);
    }
  }

  __syncthreads();  // all MFMA done; staging buffers dead; outl overlays them
#pragma unroll
  for (int fo = 0; fo < 6; ++fo) {
    int orow = obase + fo * 16 + hi4 * 4;
    f32x4 bv = *(const f32x4*)&bias[orow];
#pragma unroll
    for (int fn = 0; fn < 4; ++fn) {
      int n = nbase + fn * 16 + lo16;
#pragma unroll
      for (int r = 0; r < 4; ++r)
        outl[(orow + r) * 137 + n] = f2bf(acc[fo][fn][r] + bv[r]);
    }
  }
  __syncthreads();

  // theta rows 128..255 -> thT[b][n][c]
#pragma unroll
  for (int it = 0; it < 4; ++it) {
    int task = it * 512 + tid;
    int n = task >> 4, cc = (task & 15) << 3;
    u16 o[8];
#pragma unroll
    for (int i = 0; i < 8; ++i) o[i] = outl[(128 + cc + i) * 137 + n];
    *(s16x8*)&thT[((size_t)(b * NSP + n0 + n)) * NCI + cc] = *(s16x8*)o;
  }
  // g rows 0..127, pooled -> gp[b][c][m]
  {
    int c = tid >> 2, wq = tid & 3;
    u16 o[8];
#pragma unroll
    for (int j = 0; j < 8; ++j) {
      int w2 = wq * 8 + j;
      o[j] = bfmax4(outl[c * 137 + 2 * w2], outl[c * 137 + 2 * w2 + 1],
                    outl[c * 137 + 64 + 2 * w2], outl[c * 137 + 64 + 2 * w2 + 1]);
    }
    *(s16x8*)&gp[((size_t)(b * NCI + c)) * NM + (h2 << 5) + wq * 8] = *(s16x8*)o;
  }
  // phi rows 256..383, pooled + transposed -> phT[b][m][c]
  {
    int w2 = tid >> 4, cc = (tid & 15) << 3;
    u16 o[8];
#pragma unroll
    for (int i = 0; i < 8; ++i) {
      int c = 256 + cc + i;
      o[i] = bfmax4(outl[c * 137 + 2 * w2], outl[c * 137 + 2 * w2 + 1],
                    outl[c * 137 + 64 + 2 * w2], outl[c * 137 + 64 + 2 * w2 + 1]);
    }
    *(s16x8*)&phT[((size_t)(b * NM + (h2 << 5) + w2)) * NCI + cc] = *(s16x8*)o;
  }
}

// ---- MFMA flash attention: 32x32 swapped operands + 4-way in-block split-K ----------
// 16 waves: wave = qg(0..3) + 4*kh(0..3). Wave (qg,kh) handles 32 q, KV range
// [kh*256, kh*256+256) in 8 steps of KVBLK=32. 4 waves/SIMD hides the serial chain.
// Merge: 2-round tree (kh2->A, kh3->B; kh0+=A, kh1+=B; kh1->A; kh0+=A), then normalize.
__global__ __launch_bounds__(1024, 4) void attn_mfma(
    const u16* __restrict__ thT, const u16* __restrict__ phT,
    const u16* __restrict__ gP, u16* __restrict__ yh, u16* __restrict__ yl)
{
  __shared__ char smem[135168];  // staging: dbuf[2] x kh[4] x (phi 8K | g 8K) = 128 KB

  const int b = blockIdx.y;
  const int n0 = blockIdx.x << 7;     // 128 queries per block
  const int tid = threadIdx.x;
  const int wave = tid >> 6;
  const int qg = wave & 3;
  const int kh = wave >> 2;           // 0..3
  const int lane = tid & 63;
  const int l31 = lane & 31;
  const int hi1 = lane >> 5;
  const int qbase = n0 + (qg << 5);   // 32 q per wave
  const int swl = (l31 & 7) << 4;           // phi-tile swizzle (256 B rows)
  const int gsw = ((l31 >> 1) & 3) << 4;    // g-tile swizzle (64 B rows, row-pair)

  // theta B-fragments in registers
  s16x8 thb[8];
  {
    const u16* tr = &thT[((size_t)b * NSP + qbase + l31) * NCI + hi1 * 8];
#pragma unroll
    for (int kc = 0; kc < 8; ++kc) thb[kc] = *(const s16x8*)&tr[kc * 16];
  }

  f32x16 yacc[4];
#pragma unroll
  for (int ct = 0; ct < 4; ++ct) yacc[ct] = (f32x16)0.f;
  float m_i = -3e38f, l_i = 0.f;

  // stage step `step` for ALL 4 kh ranges into buffer s.
  // Buffer layout: + kh*16384: phi [32 m][256 B] @0, g [128 c][64 B] @8192.
  auto stage = [&](int s, int step) {
    char* base = smem + s * 65536;
#pragma unroll
    for (int it = 0; it < 4; ++it) {              // it = kh' (compile-time region)
      const int m0 = (it * 8 + step) << 5;
      char* reg = base + it * 16384;
      if (tid < 512) {                            // phi: 512 chunks (wave-uniform split)
        int m = tid >> 4, cb = (tid & 15) << 4;
        const char* src = (const char*)phT + (((size_t)b * NM + m0 + m) << 8) + (cb ^ ((m & 7) << 4));
        GLL(src, reg + (size_t)(tid & ~63) * 16);
      } else {                                    // g: 512 chunks
        int c2 = tid - 512;
        int c = c2 >> 2, mb = (c2 & 3) << 4;
        const char* src = (const char*)gP + (((size_t)b * NCI + c) << 11) + m0 * 2 + (mb ^ (((c >> 1) & 3) << 4));
        GLL(src, reg + 8192 + (size_t)(c2 & ~63) * 16);
      }
    }
  };

  stage(0, 0);
  __syncthreads();
  int cur = 0;

  for (int step = 0; step < 8; ++step) {
    if (step < 7) stage(cur ^ 1, step + 1);
    const char* ph = smem + cur * 65536 + kh * 16384;
    const char* gg = ph + 8192;

    // QK^T: D[m][q], 32 m-rows, col q = l31
    f32x16 s0 = (f32x16)0.f;
    __builtin_amdgcn_s_setprio(1);
#pragma unroll
    for (int kc = 0; kc < 8; ++kc) {
      s16x8 a0 = *(const s16x8*)(ph + l31 * 256 + ((kc * 32 + hi1 * 16) ^ swl));
      s0 = __builtin_amdgcn_mfma_f32_32x32x16_bf16(a0, thb[kc], s0, 0, 0, 0);
    }
    __builtin_amdgcn_s_setprio(0);

    // online softmax (always rescale; f32)
    float pm = s0[0];
#pragma unroll
    for (int i = 1; i < 16; ++i) pm = fmaxf(pm, s0[i]);
    pm = fmaxf(pm, __shfl_xor(pm, 32));
    float mn = fmaxf(m_i, pm);
    float sc = __expf(m_i - mn);
    float rs = 0.f;
#pragma unroll
    for (int i = 0; i < 16; ++i) { s0[i] = __expf(s0[i] - mn); rs += s0[i]; }
    rs += __shfl_xor(rs, 32);
    l_i = l_i * sc + rs;
    m_i = mn;
#pragma unroll
    for (int ct = 0; ct < 4; ++ct)
#pragma unroll
      for (int i = 0; i < 16; ++i) yacc[ct][i] *= sc;

    // P^T B-fragments in-register: cvt_pk + permlane32_swap
    s16x8 pb[2];
#pragma unroll
    for (int km = 0; km < 2; ++km) {
      int r0 = km * 8;
      unsigned X0 = cvtpk(s0[r0 + 0], s0[r0 + 1]);
      unsigned X1 = cvtpk(s0[r0 + 2], s0[r0 + 3]);
      unsigned X2 = cvtpk(s0[r0 + 4], s0[r0 + 5]);
      unsigned X3 = cvtpk(s0[r0 + 6], s0[r0 + 7]);
      asm volatile("v_permlane32_swap_b32 %0, %1" : "+v"(X0), "+v"(X2));
      asm volatile("v_permlane32_swap_b32 %0, %1" : "+v"(X1), "+v"(X3));
      unsigned d[4] = {X0, X1, X2, X3};
      pb[km] = *(s16x8*)d;
    }

    // PV: yacc[ct] (rows c = ct*32+crow, cols q) += g-frag x P^T-frag
    __builtin_amdgcn_s_setprio(1);
#pragma unroll
    for (int ct = 0; ct < 4; ++ct) {
      const char* grow = gg + (ct * 32 + l31) * 64;
#pragma unroll
      for (int km = 0; km < 2; ++km) {
        s16x8 ga = *(const s16x8*)(grow + ((km * 32 + hi1 * 16) ^ gsw));
        yacc[ct] = __builtin_amdgcn_mfma_f32_32x32x16_bf16(ga, pb[km], yacc[ct], 0, 0, 0);
      }
    }
    __builtin_amdgcn_s_setprio(0);

    __syncthreads();
    cur ^= 1;
  }

  // ---- 4-way split-K merge (2-round tree, exact online-softmax combine) ----
  float* yxA = (float*)smem;                   // 64 KB
  float* yxB = (float*)(smem + 65536);         // 64 KB
  float* mlA = (float*)(smem + 131072);        // 2 KB
  float* mlB = (float*)(smem + 133120);        // 2 KB
  const int slot = (qg << 6) + lane;           // 0..255

  auto deposit = [&](float* yx, float* ml) {
#pragma unroll
    for (int ct = 0; ct < 4; ++ct)
#pragma unroll
      for (int i4 = 0; i4 < 4; ++i4) {
        f32x4 v = {yacc[ct][i4 * 4 + 0], yacc[ct][i4 * 4 + 1],
                   yacc[ct][i4 * 4 + 2], yacc[ct][i4 * 4 + 3]};
        *(f32x4*)((char*)yx + (size_t)(((ct * 4 + i4) << 8) + slot) * 16) = v;
      }
    ml[slot * 2] = m_i;
    ml[slot * 2 + 1] = l_i;
  };
  auto mergein = [&](const float* yx, const float* ml) {
    float m1 = ml[slot * 2], l1 = ml[slot * 2 + 1];
    float mm = fmaxf(m_i, m1);
    float sc0 = __expf(m_i - mm), sc1 = __expf(m1 - mm);
    l_i = l_i * sc0 + l1 * sc1;
    m_i = mm;
#pragma unroll
    for (int ct = 0; ct < 4; ++ct)
#pragma unroll
      for (int i4 = 0; i4 < 4; ++i4) {
        f32x4 v = *(const f32x4*)((const char*)yx + (size_t)(((ct * 4 + i4) << 8) + slot) * 16);
#pragma unroll
        for (int j = 0; j < 4; ++j)
          yacc[ct][i4 * 4 + j] = yacc[ct][i4 * 4 + j] * sc0 + v[j] * sc1;
      }
  };

  if (kh == 2) deposit(yxA, mlA);
  if (kh == 3) deposit(yxB, mlB);
  __syncthreads();
  if (kh == 0) mergein(yxA, mlA);
  if (kh == 1) mergein(yxB, mlB);
  __syncthreads();
  if (kh == 1) deposit(yxA, mlA);
  __syncthreads();
  if (kh >= 1) return;
  mergein(yxA, mlA);

  float inv = 1.f / l_i;
#pragma unroll
  for (int ct = 0; ct < 4; ++ct)
#pragma unroll
    for (int i = 0; i < 16; ++i) yacc[ct][i] *= inv;

  // epilogue (kh0's 4 waves, wave-private bounce in dead region B -> coalesced writes)
  u16* bounce = (u16*)(smem + 65536) + qg * 4224;   // [32 q][132]
  const int qq = lane >> 1, c0 = (lane & 1) << 6;
#pragma unroll
  for (int pass = 0; pass < 2; ++pass) {
#pragma unroll
    for (int ct = 0; ct < 4; ++ct) {
#pragma unroll
      for (int rp = 0; rp < 8; ++rp) {
        int r = rp * 2;
        int c = ct * 32 + (r & 3) + 8 * (r >> 2) + 4 * hi1;
        float v0 = yacc[ct][r], v1 = yacc[ct][r + 1];
        u16 h0 = f2bf(v0), h1 = f2bf(v1);
        u16 w0 = h0, w1 = h1;
        if (pass) { w0 = f2bf(v0 - bf2f(h0)); w1 = f2bf(v1 - bf2f(h1)); }
        *(unsigned*)&bounce[l31 * 132 + c] = (unsigned)w0 | ((unsigned)w1 << 16);
      }
    }
    asm volatile("s_waitcnt lgkmcnt(0)" ::: "memory");
    u16* dst = pass ? yl : yh;
    size_t row = ((size_t)b * NSP + qbase + qq) * NCI + c0;
#pragma unroll
    for (int k = 0; k < 8; ++k)
      *(s16x8*)&dst[row + k * 8] = *(const s16x8*)&bounce[qq * 132 + c0 + k * 8];
    asm volatile("s_waitcnt lgkmcnt(0)" ::: "memory");
  }
}

// ---- W conv 3-pass split MFMA + fused BN stats; wy f32 (mandatory, see OFF_WY) -----
__global__ __launch_bounds__(512, 1) void conv_w_mfma(
    const u16* __restrict__ yh, const u16* __restrict__ yl,
    const u16* __restrict__ wwh, const u16* __restrict__ wwl,
    const float* __restrict__ bw, float* __restrict__ wy,
    float* __restrict__ s1g, float* __restrict__ s2g)
{
  __shared__ char smem[102400];
  u16* wsh = (u16*)smem;                  // [256 o][64 k] 32 KB swizzled
  u16* wsl = (u16*)(smem + 32768);
  u16* ysh = (u16*)(smem + 65536);        // [128 n][64 k] 16 KB
  u16* ysl = (u16*)(smem + 81920);
  float (*sums1)[256] = (float(*)[256])(smem + 98304);
  float (*sums2)[256] = (float(*)[256])(smem + 100352);

  const int b = blockIdx.y, n0 = blockIdx.x << 7;
  const int tid = threadIdx.x;
  const int wave = tid >> 6, lane = tid & 63;
  const int lo16 = lane & 15, hi4 = lane >> 4;
  const int wr = wave >> 1, wc = wave & 1;
  const int obase = wr * 64, nbase = wc * 64;

  f32x4 acc[4][4];
#pragma unroll
  for (int i = 0; i < 4; ++i)
#pragma unroll
    for (int j = 0; j < 4; ++j) acc[i][j] = (f32x4){0.f, 0.f, 0.f, 0.f};

  for (int step = 0; step < 2; ++step) {
    __syncthreads();
#pragma unroll
    for (int i = 0; i < 4; ++i) {
      int ci = i * 512 + tid;
      int o = ci >> 3, slot = ci & 7;
      size_t rowb = (size_t)o * 256 + step * 128 + ((slot ^ (o & 7)) << 4);
      GLL((const char*)wwh + rowb, (char*)wsh + (size_t)(i * 512 + (tid & ~63)) * 16);
      GLL((const char*)wwl + rowb, (char*)wsl + (size_t)(i * 512 + (tid & ~63)) * 16);
    }
#pragma unroll
    for (int i = 0; i < 2; ++i) {
      int ci = i * 512 + tid;
      int n = ci >> 3, slot = ci & 7;
      size_t rowb = ((size_t)(b * NSP + n0 + n)) * 256 + step * 128 + ((slot ^ (n & 7)) << 4);
      GLL((const char*)yh + rowb, (char*)ysh + (size_t)(i * 512 + (tid & ~63)) * 16);
      GLL((const char*)yl + rowb, (char*)ysl + (size_t)(i * 512 + (tid & ~63)) * 16);
    }
    __syncthreads();

#pragma unroll
    for (int kc = 0; kc < 2; ++kc) {
      const int sl = kc * 4 + hi4;
      s16x8 bfh[4], bfl[4];
#pragma unroll
      for (int fn = 0; fn < 4; ++fn) {
        int n = nbase + fn * 16 + lo16;
        int off = (int)n * 128 + ((sl ^ (n & 7)) << 4);
        bfh[fn] = *(const s16x8*)((const char*)ysh + off);
        bfl[fn] = *(const s16x8*)((const char*)ysl + off);
      }
      __builtin_amdgcn_s_setprio(1);
#pragma unroll
      for (int fo = 0; fo < 4; ++fo) {
        int o = obase + fo * 16 + lo16;
        int off = (int)o * 128 + ((sl ^ (o & 7)) << 4);
        s16x8 afh = *(const s16x8*)((const char*)wsh + off);
        s16x8 afl = *(const s16x8*)((const char*)wsl + off);
#pragma unroll
        for (int fn = 0; fn < 4; ++fn) {
          acc[fo][fn] = __builtin_amdgcn_mfma_f32_16x16x32_bf16(afh, bfh[fn], acc[fo][fn], 0, 0, 0);
          acc[fo][fn] = __builtin_amdgcn_mfma_f32_16x16x32_bf16(afh, bfl[fn], acc[fo][fn], 0, 0, 0);
          acc[fo][fn] = __builtin_amdgcn_mfma_f32_16x16x32_bf16(afl, bfh[fn], acc[fo][fn], 0, 0, 0);
        }
      }
      __builtin_amdgcn_s_setprio(0);
    }
  }

  // epilogue: bias, write wy (f32), BN partial stats
#pragma unroll
  for (int fo = 0; fo < 4; ++fo) {
    int orow = obase + fo * 16 + hi4 * 4;
    float bv[4];
#pragma unroll
    for (int r = 0; r < 4; ++r) bv[r] = bw[orow + r];
    float ss[4] = {0.f, 0.f, 0.f, 0.f}, sq[4] = {0.f, 0.f, 0.f, 0.f};
#pragma unroll
    for (int fn = 0; fn < 4; ++fn) {
      int col = n0 + nbase + fn * 16 + lo16;
#pragma unroll
      for (int r = 0; r < 4; ++r) {
        float v = acc[fo][fn][r] + bv[r];
        wy[((size_t)(b * NC) + orow + r) * NSP + col] = v;
        ss[r] += v;
        sq[r] += v * v;
      }
    }
#pragma unroll
    for (int r = 0; r < 4; ++r) {
#pragma unroll
      for (int d = 1; d < 16; d <<= 1) {
        ss[r] += __shfl_xor(ss[r], d);
        sq[r] += __shfl_xor(sq[r], d);
      }
    }
    if (lo16 == 0) {
#pragma unroll
      for (int r = 0; r < 4; ++r) {
        sums1[wc][orow + r] = ss[r];
        sums2[wc][orow + r] = sq[r];
      }
    }
  }
  __syncthreads();
  if (tid < 256) {
    atomicAdd(&s1g[tid], sums1[0][tid] + sums1[1][tid]);
    atomicAdd(&s2g[tid], sums2[0][tid] + sums2[1][tid]);
  }
}

// ---- BN (batch stats) + affine + residual, float4 ----------------------------------
__global__ __launch_bounds__(256) void bn_res4(
    const float* __restrict__ wy, const float* __restrict__ x,
    const float* __restrict__ s1, const float* __restrict__ s2,
    const float* __restrict__ gamma, const float* __restrict__ beta,
    float* __restrict__ out)
{
  int i4 = (blockIdx.x * 256 + threadIdx.x) << 2;
  int c = (i4 >> 12) & 255;
  const float cnt = 1.f / 32768.f;
  float mean = s1[c] * cnt;
  float var = s2[c] * cnt - mean * mean;
  float inv = rsqrtf(var + 1e-5f) * gamma[c];
  float bet = beta[c];
  float4 w = *(const float4*)&wy[i4];
  float4 xv = *(const float4*)&x[i4];
  float4 o;
  o.x = (w.x - mean) * inv + bet + xv.x;
  o.y = (w.y - mean) * inv + bet + xv.y;
  o.z = (w.z - mean) * inv + bet + xv.z;
  o.w = (w.w - mean) * inv + bet + xv.w;
  *(float4*)&out[i4] = o;
}

extern "C" void kernel_launch(void* const* d_in, const int* in_sizes, int n_in,
                              void* d_out, int out_size, void* d_ws, size_t ws_size,
                              hipStream_t stream) {
  const float* x    = (const float*)d_in[0];
  const float* w_g  = (const float*)d_in[1];
  const float* b_g  = (const float*)d_in[2];
  const float* w_th = (const float*)d_in[3];
  const float* b_th = (const float*)d_in[4];
  const float* w_ph = (const float*)d_in[5];
  const float* b_ph = (const float*)d_in[6];
  const float* w_w  = (const float*)d_in[7];
  const float* b_w  = (const float*)d_in[8];
  const float* gam  = (const float*)d_in[9];
  const float* bet  = (const float*)d_in[10];
  float* out = (float*)d_out;
  char* ws = (char*)d_ws;

  u16*   xh  = (u16*)(ws + OFF_XH);
  u16*   xl  = (u16*)(ws + OFF_XL);
  u16*   thT = (u16*)(ws + OFF_THT);
  u16*   phT = (u16*)(ws + OFF_PHT);
  u16*   gp  = (u16*)(ws + OFF_GP);
  u16*   yhb = (u16*)(ws + OFF_YH);
  u16*   ylb = (u16*)(ws + OFF_YL);
  float* wy  = (float*)(ws + OFF_WY);
  u16*   wbh = (u16*)(ws + OFF_WBH);
  u16*   wbl = (u16*)(ws + OFF_WBL);
  u16*   wwh = (u16*)(ws + OFF_WWH);
  u16*   wwl = (u16*)(ws + OFF_WWL);
  float* s1  = (float*)(ws + OFF_S);
  float* s2  = s1 + 256;

  wcvt<<<dim3(512), 256, 0, stream>>>(w_g, w_th, w_ph, w_w, wbh, wbl, wwh, wwl);
  zero_stats<<<dim3(1), 512, 0, stream>>>(s1);
  xt_cvt<<<dim3(64, 4, 8), 256, 0, stream>>>(x, xh, xl);

  proj_fused<<<dim3(32, 8), 512, 0, stream>>>(xh, xl, wbh, wbl, b_g, b_th, b_ph, thT, phT, gp);

  attn_mfma<<<dim3(32, 8), 1024, 0, stream>>>(thT, phT, gp, yhb, ylb);

  conv_w_mfma<<<dim3(32, 8), 512, 0, stream>>>(yhb, ylb, wwh, wwl, b_w, wy, s1, s2);

  bn_res4<<<dim3(8192), 256, 0, stream>>>(wy, x, s1, s2, gam, bet, out);
}

// Round 11
// 104.608 us; speedup vs baseline: 1.3249x; 1.3249x over previous
//
#include <hip/hip_runtime.h>
#include <hip/hip_bf16.h>

// Problem constants: B=8, C=256, Ci=128, H=W=64, N=4096, M=1024
#define NB 8
#define NC 256
#define NCI 128
#define NSP 4096
#define NM 1024

typedef float f32x4 __attribute__((ext_vector_type(4)));
typedef float f32x16 __attribute__((ext_vector_type(16)));
typedef short s16x8 __attribute__((ext_vector_type(8)));
typedef unsigned short u16;

// Workspace layout (byte offsets, total < 64 MB)
#define OFF_XH  (0ull)              // xh bf16 [B][N][C]  16 MB (dead after proj)
#define OFF_THT (33554432ull)       // thT bf16 [B][N][Ci] 8 MB (dead after attn)
#define OFF_PHT (41943040ull)       // phT bf16 [B][M][Ci] 2 MB
#define OFF_GP  (44040192ull)       // gp  bf16 [B][Ci][M] 2 MB
#define OFF_YH  (46137344ull)       // yh  bf16 [B][N][Ci] 8 MB
#define OFF_YL  (54525952ull)       // yl  bf16 [B][N][Ci] 8 MB
#define OFF_WY  (0ull)              // wy f32 [B][C][N] 32 MB (overlays XH, dead)
// NOTE: wy MUST be f32. BN divides by per-channel sigma(wy) which is tiny vs |mean(wy)|
// (attention output nearly constant over n) -> bf16 wy quantization (|mean|*2^-9/sigma)
// lands ~0.25 on the output. Measured twice (rounds 5, 8).
// NOTE: attn split-K>2 in-block needs 16 waves/CU -> 128 VGPR cap < ~150 live state ->
// scratch spill (round 10: WRITE_SIZE 16->52MB, attn 35->63us). Keep split-K x2.
#define OFF_WBH (62914560ull)       // wb hi bf16 [384][256] 192 KB
#define OFF_WBL (63111168ull)       // wb lo
#define OFF_WWH (63307776ull)       // wwb hi bf16 [256][128] 64 KB
#define OFF_WWL (63373312ull)       // wwb lo
#define OFF_S   (63438848ull)       // s1[256], s2[256] f32

#define GLL(src, dst) __builtin_amdgcn_global_load_lds( \
    (const __attribute__((address_space(1))) unsigned*)(src), \
    (__attribute__((address_space(3))) unsigned*)(dst), 16, 0, 0)

__device__ __forceinline__ u16 f2bf(float f) {
  union { __hip_bfloat16 h; u16 u; } v;
  v.h = __float2bfloat16(f);
  return v.u;
}
__device__ __forceinline__ float bf2f(u16 u) {
  union { unsigned u; float f; } v;
  v.u = (unsigned)u << 16;
  return v.f;
}
__device__ __forceinline__ u16 bfmax4(u16 a, u16 b, u16 c, u16 d) {
  float v = fmaxf(fmaxf(bf2f(a), bf2f(b)), fmaxf(bf2f(c), bf2f(d)));
  return f2bf(v);
}
__device__ __forceinline__ unsigned cvtpk(float lo, float hi) {
  unsigned r;
  asm volatile("v_cvt_pk_bf16_f32 %0, %1, %2" : "=v"(r) : "v"(lo), "v"(hi));
  return r;
}

__global__ void zero_stats(float* s) { s[threadIdx.x] = 0.f; }

// ---- weights -> bf16 hi/lo (wb stacked: rows 0-127 g, 128-255 theta, 256-383 phi) --
__global__ __launch_bounds__(256) void wcvt(
    const float* __restrict__ wg, const float* __restrict__ wth,
    const float* __restrict__ wph, const float* __restrict__ ww,
    u16* __restrict__ wbh, u16* __restrict__ wbl,
    u16* __restrict__ wwh, u16* __restrict__ wwl)
{
  int idx = blockIdx.x * 256 + threadIdx.x;
  if (idx < 384 * 256) {
    int row = idx >> 8, k = idx & 255;
    float v = row < 128 ? wg[row * 256 + k]
            : row < 256 ? wth[(row - 128) * 256 + k]
                        : wph[(row - 256) * 256 + k];
    u16 h = f2bf(v);
    wbh[idx] = h;
    wbl[idx] = f2bf(v - bf2f(h));
  } else {
    int j = idx - 384 * 256;
    float v = ww[j];
    u16 h = f2bf(v);
    wwh[j] = h;
    wwl[j] = f2bf(v - bf2f(h));
  }
}

// ---- x [B][C][N] f32 -> xh [B][N][C] bf16 (transpose + cvt; xl dropped: see theory) -
__global__ __launch_bounds__(256) void xt_cvt(const float* __restrict__ x,
                                              u16* __restrict__ xh)
{
  __shared__ float t[64 * 68];
  const int n0 = blockIdx.x << 6, c0 = blockIdx.y << 6, b = blockIdx.z;
  const int tid = threadIdx.x;
  const int cl = tid >> 4, n4 = (tid & 15) << 2;
#pragma unroll
  for (int it = 0; it < 4; ++it) {
    int c = it * 16 + cl;
    float4 v = *(const float4*)&x[((size_t)(b * NC + c0 + c)) * NSP + n0 + n4];
    *(float4*)&t[c * 68 + n4] = v;
  }
  __syncthreads();
#pragma unroll
  for (int it = 0; it < 2; ++it) {
    int task = it * 256 + tid;
    int n = task >> 3, cc = (task & 7) << 3;
    u16 oh[8];
#pragma unroll
    for (int i = 0; i < 8; ++i) oh[i] = f2bf(t[(cc + i) * 68 + n]);
    *(s16x8*)&xh[((size_t)(b * NSP + n0 + n)) * NC + c0 + cc] = *(s16x8*)oh;
  }
}

// ---- fused projection: 384 channels, 2-pass (wh+wl)*xh MFMA, bias+pool+layouts -----
__global__ __launch_bounds__(512, 1) void proj_fused(
    const u16* __restrict__ xh,
    const u16* __restrict__ wbh, const u16* __restrict__ wbl,
    const float* __restrict__ bg, const float* __restrict__ bth,
    const float* __restrict__ bph,
    u16* __restrict__ thT, u16* __restrict__ phT, u16* __restrict__ gp)
{
  __shared__ char smem[116224];
  u16* xsh = (u16*)smem;                 // [128 n][64 k]  16 KB swizzled
  u16* wsh = (u16*)(smem + 16384);       // [384 o][64 k]  48 KB
  u16* wsl = (u16*)(smem + 65536);       // [384 o][64 k]  48 KB
  u16* outl = (u16*)smem;                // epilogue [384][137] bf16 overlay
  float* bias = (float*)(smem + 114688); // 384 f32

  const int b = blockIdx.y, h2 = blockIdx.x;
  const int n0 = h2 << 7;
  const int tid = threadIdx.x;
  const int wave = tid >> 6, lane = tid & 63;
  const int lo16 = lane & 15, hi4 = lane >> 4;
  const int wr = wave >> 1, wc = wave & 1;
  const int obase = wr * 96, nbase = wc * 64;

  if (tid < 384)
    bias[tid] = tid < 128 ? bg[tid] : tid < 256 ? bth[tid - 128] : bph[tid - 256];

  f32x4 acc[6][4];
#pragma unroll
  for (int i = 0; i < 6; ++i)
#pragma unroll
    for (int j = 0; j < 4; ++j) acc[i][j] = (f32x4){0.f, 0.f, 0.f, 0.f};

  for (int step = 0; step < 4; ++step) {
    __syncthreads();
#pragma unroll
    for (int i = 0; i < 2; ++i) {
      int ci = i * 512 + tid;
      int n = ci >> 3, slot = ci & 7;
      size_t rowb = ((size_t)(b * NSP + n0 + n)) * 512 + step * 128 + ((slot ^ (n & 7)) << 4);
      GLL((const char*)xh + rowb, (char*)xsh + (size_t)(i * 512 + (tid & ~63)) * 16);
    }
#pragma unroll
    for (int i = 0; i < 6; ++i) {
      int ci = i * 512 + tid;
      int o = ci >> 3, slot = ci & 7;
      size_t rowb = (size_t)o * 512 + step * 128 + ((slot ^ (o & 7)) << 4);
      GLL((const char*)wbh + rowb, (char*)wsh + (size_t)(i * 512 + (tid & ~63)) * 16);
      GLL((const char*)wbl + rowb, (char*)wsl + (size_t)(i * 512 + (tid & ~63)) * 16);
    }
    __syncthreads();

#pragma unroll
    for (int kc = 0; kc < 2; ++kc) {
      const int sl = kc * 4 + hi4;
      s16x8 bfh[4];
#pragma unroll
      for (int fn = 0; fn < 4; ++fn) {
        int n = nbase + fn * 16 + lo16;
        bfh[fn] = *(const s16x8*)((const char*)xsh + (int)n * 128 + ((sl ^ (n & 7)) << 4));
      }
      __builtin_amdgcn_s_setprio(1);
#pragma unroll
      for (int fo = 0; fo < 6; ++fo) {
        int o = obase + fo * 16 + lo16;
        int off = (int)o * 128 + ((sl ^ (o & 7)) << 4);
        s16x8 afh = *(const s16x8*)((const char*)wsh + off);
        s16x8 afl = *(const s16x8*)((const char*)wsl + off);
#pragma unroll
        for (int fn = 0; fn < 4; ++fn) {
          acc[fo][fn] = __builtin_amdgcn_mfma_f32_16x16x32_bf16(afh, bfh[fn], acc[fo][fn], 0, 0, 0);
          acc[fo][fn] = __builtin_amdgcn_mfma_f32_16x16x32_bf16(afl, bfh[fn], acc[fo][fn], 0, 0, 0);
        }
      }
      __builtin_amdgcn_s_setprio(0);
    }
  }

  __syncthreads();  // all MFMA done; staging buffers dead; outl overlays them
#pragma unroll
  for (int fo = 0; fo < 6; ++fo) {
    int orow = obase + fo * 16 + hi4 * 4;
    f32x4 bv = *(const f32x4*)&bias[orow];
#pragma unroll
    for (int fn = 0; fn < 4; ++fn) {
      int n = nbase + fn * 16 + lo16;
#pragma unroll
      for (int r = 0; r < 4; ++r)
        outl[(orow + r) * 137 + n] = f2bf(acc[fo][fn][r] + bv[r]);
    }
  }
  __syncthreads();

  // theta rows 128..255 -> thT[b][n][c]
#pragma unroll
  for (int it = 0; it < 4; ++it) {
    int task = it * 512 + tid;
    int n = task >> 4, cc = (task & 15) << 3;
    u16 o[8];
#pragma unroll
    for (int i = 0; i < 8; ++i) o[i] = outl[(128 + cc + i) * 137 + n];
    *(s16x8*)&thT[((size_t)(b * NSP + n0 + n)) * NCI + cc] = *(s16x8*)o;
  }
  // g rows 0..127, pooled -> gp[b][c][m]
  {
    int c = tid >> 2, wq = tid & 3;
    u16 o[8];
#pragma unroll
    for (int j = 0; j < 8; ++j) {
      int w2 = wq * 8 + j;
      o[j] = bfmax4(outl[c * 137 + 2 * w2], outl[c * 137 + 2 * w2 + 1],
                    outl[c * 137 + 64 + 2 * w2], outl[c * 137 + 64 + 2 * w2 + 1]);
    }
    *(s16x8*)&gp[((size_t)(b * NCI + c)) * NM + (h2 << 5) + wq * 8] = *(s16x8*)o;
  }
  // phi rows 256..383, pooled + transposed -> phT[b][m][c]
  {
    int w2 = tid >> 4, cc = (tid & 15) << 3;
    u16 o[8];
#pragma unroll
    for (int i = 0; i < 8; ++i) {
      int c = 256 + cc + i;
      o[i] = bfmax4(outl[c * 137 + 2 * w2], outl[c * 137 + 2 * w2 + 1],
                    outl[c * 137 + 64 + 2 * w2], outl[c * 137 + 64 + 2 * w2 + 1]);
    }
    *(s16x8*)&phT[((size_t)(b * NM + (h2 << 5) + w2)) * NCI + cc] = *(s16x8*)o;
  }
}

// ---- MFMA flash attention: 32x32 swapped operands + in-block split-K (round-9) -----
// 8 waves: wave = qg (0..3) + 4*kh. Wave (qg,kh) handles 32 q, KV tiles kh*8..kh*8+7.
// End: kh=1 deposits raw (yacc,m,l) to LDS; kh=0 merges (exact online-softmax combine).
__global__ __launch_bounds__(512, 2) void attn_mfma(
    const u16* __restrict__ thT, const u16* __restrict__ phT,
    const u16* __restrict__ gP, u16* __restrict__ yh, u16* __restrict__ yl)
{
  __shared__ char smem[131072];  // dbuf[2] x half[2] x (phi 16K | g 16K)

  const int b = blockIdx.y;
  const int n0 = blockIdx.x << 7;     // 128 queries per block
  const int tid = threadIdx.x;
  const int wave = tid >> 6;
  const int qg = wave & 3;
  const int kh = wave >> 2;
  const int lane = tid & 63;
  const int l31 = lane & 31;
  const int hi1 = lane >> 5;
  const int qbase = n0 + (qg << 5);   // 32 q per wave
  const int swl = (l31 & 7) << 4;

  // theta B-fragments in registers
  s16x8 thb[8];
  {
    const u16* tr = &thT[((size_t)b * NSP + qbase + l31) * NCI + hi1 * 8];
#pragma unroll
    for (int kc = 0; kc < 8; ++kc) thb[kc] = *(const s16x8*)&tr[kc * 16];
  }

  f32x16 yacc[4];
#pragma unroll
  for (int ct = 0; ct < 4; ++ct) yacc[ct] = (f32x16)0.f;
  float m_i = -3e38f, l_i = 0.f;

  // stage tiles (step) and (step+8) into buf s: regions [h0phi][h0g][h1phi][h1g]
  auto stage = [&](int s, int step) {
    char* base = smem + s * 65536;
    const int m0a = step << 6, m0b = (step + 8) << 6;
#pragma unroll
    for (int it = 0; it < 8; ++it) {
      const int rg = it >> 1;                       // compile-time region
      int r = ((it & 1) << 9) + tid;                // chunk within region, 0..1023
      char* dst = base + rg * 16384 + (size_t)(((it & 1) << 9) + (tid & ~63)) * 16;
      if (rg == 0 || rg == 2) {
        int m0 = (rg == 0) ? m0a : m0b;
        int m = r >> 4, cb = (r & 15) << 4;
        const char* src = (const char*)phT + (((size_t)b * NM + m0 + m) << 8) + (cb ^ ((m & 7) << 4));
        GLL(src, dst);
      } else {
        int m0 = (rg == 1) ? m0a : m0b;
        int c = r >> 3, mb = (r & 7) << 4;
        const char* src = (const char*)gP + (((size_t)b * NCI + c) << 11) + m0 * 2 + (mb ^ ((c & 7) << 4));
        GLL(src, dst);
      }
    }
  };

  stage(0, 0);
  __syncthreads();
  int cur = 0;

  for (int step = 0; step < 8; ++step) {
    if (step < 7) stage(cur ^ 1, step + 1);
    const char* ph = smem + cur * 65536 + kh * 32768;
    const char* gg = ph + 16384;

    // QK^T: D[m][q], col q = l31
    f32x16 s0 = (f32x16)0.f, s1 = (f32x16)0.f;
    __builtin_amdgcn_s_setprio(1);
#pragma unroll
    for (int kc = 0; kc < 8; ++kc) {
      int cofs = (kc * 32 + hi1 * 16);
      s16x8 a0 = *(const s16x8*)(ph + l31 * 256 + (cofs ^ swl));
      s16x8 a1 = *(const s16x8*)(ph + (32 + l31) * 256 + (cofs ^ swl));
      s0 = __builtin_amdgcn_mfma_f32_32x32x16_bf16(a0, thb[kc], s0, 0, 0, 0);
      s1 = __builtin_amdgcn_mfma_f32_32x32x16_bf16(a1, thb[kc], s1, 0, 0, 0);
    }
    __builtin_amdgcn_s_setprio(0);

    // online softmax (always rescale; f32)
    float pm = s0[0];
#pragma unroll
    for (int i = 1; i < 16; ++i) pm = fmaxf(pm, s0[i]);
#pragma unroll
    for (int i = 0; i < 16; ++i) pm = fmaxf(pm, s1[i]);
    pm = fmaxf(pm, __shfl_xor(pm, 32));
    float mn = fmaxf(m_i, pm);
    float sc = __expf(m_i - mn);
    float rs = 0.f;
#pragma unroll
    for (int i = 0; i < 16; ++i) { s0[i] = __expf(s0[i] - mn); rs += s0[i]; }
#pragma unroll
    for (int i = 0; i < 16; ++i) { s1[i] = __expf(s1[i] - mn); rs += s1[i]; }
    rs += __shfl_xor(rs, 32);
    l_i = l_i * sc + rs;
    m_i = mn;
#pragma unroll
    for (int ct = 0; ct < 4; ++ct)
#pragma unroll
      for (int i = 0; i < 16; ++i) yacc[ct][i] *= sc;

    // P^T B-fragments in-register: cvt_pk + permlane32_swap
    s16x8 pb[4];
#pragma unroll
    for (int km = 0; km < 4; ++km) {
      int r0 = (km & 1) * 8;
      unsigned X0, X1, X2, X3;
      if (km < 2) {
        X0 = cvtpk(s0[r0 + 0], s0[r0 + 1]);
        X1 = cvtpk(s0[r0 + 2], s0[r0 + 3]);
        X2 = cvtpk(s0[r0 + 4], s0[r0 + 5]);
        X3 = cvtpk(s0[r0 + 6], s0[r0 + 7]);
      } else {
        X0 = cvtpk(s1[r0 + 0], s1[r0 + 1]);
        X1 = cvtpk(s1[r0 + 2], s1[r0 + 3]);
        X2 = cvtpk(s1[r0 + 4], s1[r0 + 5]);
        X3 = cvtpk(s1[r0 + 6], s1[r0 + 7]);
      }
      asm volatile("v_permlane32_swap_b32 %0, %1" : "+v"(X0), "+v"(X2));
      asm volatile("v_permlane32_swap_b32 %0, %1" : "+v"(X1), "+v"(X3));
      unsigned d[4] = {X0, X1, X2, X3};
      pb[km] = *(s16x8*)d;
    }

    // PV
    __builtin_amdgcn_s_setprio(1);
#pragma unroll
    for (int ct = 0; ct < 4; ++ct) {
      const char* grow = gg + (ct * 32 + l31) * 128;
#pragma unroll
      for (int km = 0; km < 4; ++km) {
        s16x8 ga = *(const s16x8*)(grow + ((km * 32 + hi1 * 16) ^ swl));
        yacc[ct] = __builtin_amdgcn_mfma_f32_32x32x16_bf16(ga, pb[km], yacc[ct], 0, 0, 0);
      }
    }
    __builtin_amdgcn_s_setprio(0);

    __syncthreads();
    cur ^= 1;
  }

  // ---- split-K merge ----
  float* yx = (float*)smem;               // [16 chunks][256 slots][4 f32] = 64 KB
  float* ml = (float*)(smem + 65536);     // [256 slots][2 f32]
  const int slot = (qg << 6) + lane;
  if (kh == 1) {
#pragma unroll
    for (int ct = 0; ct < 4; ++ct)
#pragma unroll
      for (int i4 = 0; i4 < 4; ++i4) {
        f32x4 v = {yacc[ct][i4 * 4 + 0], yacc[ct][i4 * 4 + 1],
                   yacc[ct][i4 * 4 + 2], yacc[ct][i4 * 4 + 3]};
        *(f32x4*)((char*)yx + (size_t)(((ct * 4 + i4) << 8) + slot) * 16) = v;
      }
    ml[slot * 2] = m_i;
    ml[slot * 2 + 1] = l_i;
  }
  __syncthreads();
  if (kh == 1) return;

  float m1 = ml[slot * 2], l1 = ml[slot * 2 + 1];
  float mm = fmaxf(m_i, m1);
  float sc0 = __expf(m_i - mm), sc1 = __expf(m1 - mm);
  float inv = 1.f / (l_i * sc0 + l1 * sc1);
  float a0 = sc0 * inv, a1 = sc1 * inv;
#pragma unroll
  for (int ct = 0; ct < 4; ++ct)
#pragma unroll
    for (int i4 = 0; i4 < 4; ++i4) {
      f32x4 v = *(const f32x4*)((const char*)yx + (size_t)(((ct * 4 + i4) << 8) + slot) * 16);
#pragma unroll
      for (int j = 0; j < 4; ++j)
        yacc[ct][i4 * 4 + j] = yacc[ct][i4 * 4 + j] * a0 + v[j] * a1;
    }

  // epilogue (waves 0-3 only, wave-private bounce -> coalesced yh/yl writes)
  u16* bounce = (u16*)(smem + 67584) + qg * 4224;   // [32 q][132]
  const int qq = lane >> 1, c0 = (lane & 1) << 6;
#pragma unroll
  for (int pass = 0; pass < 2; ++pass) {
#pragma unroll
    for (int ct = 0; ct < 4; ++ct) {
#pragma unroll
      for (int rp = 0; rp < 8; ++rp) {
        int r = rp * 2;
        int c = ct * 32 + (r & 3) + 8 * (r >> 2) + 4 * hi1;
        float v0 = yacc[ct][r], v1 = yacc[ct][r + 1];
        u16 h0 = f2bf(v0), h1 = f2bf(v1);
        u16 w0 = h0, w1 = h1;
        if (pass) { w0 = f2bf(v0 - bf2f(h0)); w1 = f2bf(v1 - bf2f(h1)); }
        *(unsigned*)&bounce[l31 * 132 + c] = (unsigned)w0 | ((unsigned)w1 << 16);
      }
    }
    asm volatile("s_waitcnt lgkmcnt(0)" ::: "memory");
    u16* dst = pass ? yl : yh;
    size_t row = ((size_t)b * NSP + qbase + qq) * NCI + c0;
#pragma unroll
    for (int k = 0; k < 8; ++k)
      *(s16x8*)&dst[row + k * 8] = *(const s16x8*)&bounce[qq * 132 + c0 + k * 8];
    asm volatile("s_waitcnt lgkmcnt(0)" ::: "memory");
  }
}

// ---- W conv 3-pass split MFMA + fused BN stats; wy f32 (mandatory, see OFF_WY) -----
__global__ __launch_bounds__(512, 1) void conv_w_mfma(
    const u16* __restrict__ yh, const u16* __restrict__ yl,
    const u16* __restrict__ wwh, const u16* __restrict__ wwl,
    const float* __restrict__ bw, float* __restrict__ wy,
    float* __restrict__ s1g, float* __restrict__ s2g)
{
  __shared__ char smem[102400];
  u16* wsh = (u16*)smem;                  // [256 o][64 k] 32 KB swizzled
  u16* wsl = (u16*)(smem + 32768);
  u16* ysh = (u16*)(smem + 65536);        // [128 n][64 k] 16 KB
  u16* ysl = (u16*)(smem + 81920);
  float (*sums1)[256] = (float(*)[256])(smem + 98304);
  float (*sums2)[256] = (float(*)[256])(smem + 100352);

  const int b = blockIdx.y, n0 = blockIdx.x << 7;
  const int tid = threadIdx.x;
  const int wave = tid >> 6, lane = tid & 63;
  const int lo16 = lane & 15, hi4 = lane >> 4;
  const int wr = wave >> 1, wc = wave & 1;
  const int obase = wr * 64, nbase = wc * 64;

  f32x4 acc[4][4];
#pragma unroll
  for (int i = 0; i < 4; ++i)
#pragma unroll
    for (int j = 0; j < 4; ++j) acc[i][j] = (f32x4){0.f, 0.f, 0.f, 0.f};

  for (int step = 0; step < 2; ++step) {
    __syncthreads();
#pragma unroll
    for (int i = 0; i < 4; ++i) {
      int ci = i * 512 + tid;
      int o = ci >> 3, slot = ci & 7;
      size_t rowb = (size_t)o * 256 + step * 128 + ((slot ^ (o & 7)) << 4);
      GLL((const char*)wwh + rowb, (char*)wsh + (size_t)(i * 512 + (tid & ~63)) * 16);
      GLL((const char*)wwl + rowb, (char*)wsl + (size_t)(i * 512 + (tid & ~63)) * 16);
    }
#pragma unroll
    for (int i = 0; i < 2; ++i) {
      int ci = i * 512 + tid;
      int n = ci >> 3, slot = ci & 7;
      size_t rowb = ((size_t)(b * NSP + n0 + n)) * 256 + step * 128 + ((slot ^ (n & 7)) << 4);
      GLL((const char*)yh + rowb, (char*)ysh + (size_t)(i * 512 + (tid & ~63)) * 16);
      GLL((const char*)yl + rowb, (char*)ysl + (size_t)(i * 512 + (tid & ~63)) * 16);
    }
    __syncthreads();

#pragma unroll
    for (int kc = 0; kc < 2; ++kc) {
      const int sl = kc * 4 + hi4;
      s16x8 bfh[4], bfl[4];
#pragma unroll
      for (int fn = 0; fn < 4; ++fn) {
        int n = nbase + fn * 16 + lo16;
        int off = (int)n * 128 + ((sl ^ (n & 7)) << 4);
        bfh[fn] = *(const s16x8*)((const char*)ysh + off);
        bfl[fn] = *(const s16x8*)((const char*)ysl + off);
      }
      __builtin_amdgcn_s_setprio(1);
#pragma unroll
      for (int fo = 0; fo < 4; ++fo) {
        int o = obase + fo * 16 + lo16;
        int off = (int)o * 128 + ((sl ^ (o & 7)) << 4);
        s16x8 afh = *(const s16x8*)((const char*)wsh + off);
        s16x8 afl = *(const s16x8*)((const char*)wsl + off);
#pragma unroll
        for (int fn = 0; fn < 4; ++fn) {
          acc[fo][fn] = __builtin_amdgcn_mfma_f32_16x16x32_bf16(afh, bfh[fn], acc[fo][fn], 0, 0, 0);
          acc[fo][fn] = __builtin_amdgcn_mfma_f32_16x16x32_bf16(afh, bfl[fn], acc[fo][fn], 0, 0, 0);
          acc[fo][fn] = __builtin_amdgcn_mfma_f32_16x16x32_bf16(afl, bfh[fn], acc[fo][fn], 0, 0, 0);
        }
      }
      __builtin_amdgcn_s_setprio(0);
    }
  }

  // epilogue: bias, write wy (f32), BN partial stats
#pragma unroll
  for (int fo = 0; fo < 4; ++fo) {
    int orow = obase + fo * 16 + hi4 * 4;
    float bv[4];
#pragma unroll
    for (int r = 0; r < 4; ++r) bv[r] = bw[orow + r];
    float ss[4] = {0.f, 0.f, 0.f, 0.f}, sq[4] = {0.f, 0.f, 0.f, 0.f};
#pragma unroll
    for (int fn = 0; fn < 4; ++fn) {
      int col = n0 + nbase + fn * 16 + lo16;
#pragma unroll
      for (int r = 0; r < 4; ++r) {
        float v = acc[fo][fn][r] + bv[r];
        wy[((size_t)(b * NC) + orow + r) * NSP + col] = v;
        ss[r] += v;
        sq[r] += v * v;
      }
    }
#pragma unroll
    for (int r = 0; r < 4; ++r) {
#pragma unroll
      for (int d = 1; d < 16; d <<= 1) {
        ss[r] += __shfl_xor(ss[r], d);
        sq[r] += __shfl_xor(sq[r], d);
      }
    }
    if (lo16 == 0) {
#pragma unroll
      for (int r = 0; r < 4; ++r) {
        sums1[wc][orow + r] = ss[r];
        sums2[wc][orow + r] = sq[r];
      }
    }
  }
  __syncthreads();
  if (tid < 256) {
    atomicAdd(&s1g[tid], sums1[0][tid] + sums1[1][tid]);
    atomicAdd(&s2g[tid], sums2[0][tid] + sums2[1][tid]);
  }
}

// ---- BN (batch stats) + affine + residual, float4 ----------------------------------
__global__ __launch_bounds__(256) void bn_res4(
    const float* __restrict__ wy, const float* __restrict__ x,
    const float* __restrict__ s1, const float* __restrict__ s2,
    const float* __restrict__ gamma, const float* __restrict__ beta,
    float* __restrict__ out)
{
  int i4 = (blockIdx.x * 256 + threadIdx.x) << 2;
  int c = (i4 >> 12) & 255;
  const float cnt = 1.f / 32768.f;
  float mean = s1[c] * cnt;
  float var = s2[c] * cnt - mean * mean;
  float inv = rsqrtf(var + 1e-5f) * gamma[c];
  float bet = beta[c];
  float4 w = *(const float4*)&wy[i4];
  float4 xv = *(const float4*)&x[i4];
  float4 o;
  o.x = (w.x - mean) * inv + bet + xv.x;
  o.y = (w.y - mean) * inv + bet + xv.y;
  o.z = (w.z - mean) * inv + bet + xv.z;
  o.w = (w.w - mean) * inv + bet + xv.w;
  *(float4*)&out[i4] = o;
}

extern "C" void kernel_launch(void* const* d_in, const int* in_sizes, int n_in,
                              void* d_out, int out_size, void* d_ws, size_t ws_size,
                              hipStream_t stream) {
  const float* x    = (const float*)d_in[0];
  const float* w_g  = (const float*)d_in[1];
  const float* b_g  = (const float*)d_in[2];
  const float* w_th = (const float*)d_in[3];
  const float* b_th = (const float*)d_in[4];
  const float* w_ph = (const float*)d_in[5];
  const float* b_ph = (const float*)d_in[6];
  const float* w_w  = (const float*)d_in[7];
  const float* b_w  = (const float*)d_in[8];
  const float* gam  = (const float*)d_in[9];
  const float* bet  = (const float*)d_in[10];
  float* out = (float*)d_out;
  char* ws = (char*)d_ws;

  u16*   xh  = (u16*)(ws + OFF_XH);
  u16*   thT = (u16*)(ws + OFF_THT);
  u16*   phT = (u16*)(ws + OFF_PHT);
  u16*   gp  = (u16*)(ws + OFF_GP);
  u16*   yhb = (u16*)(ws + OFF_YH);
  u16*   ylb = (u16*)(ws + OFF_YL);
  float* wy  = (float*)(ws + OFF_WY);
  u16*   wbh = (u16*)(ws + OFF_WBH);
  u16*   wbl = (u16*)(ws + OFF_WBL);
  u16*   wwh = (u16*)(ws + OFF_WWH);
  u16*   wwl = (u16*)(ws + OFF_WWL);
  float* s1  = (float*)(ws + OFF_S);
  float* s2  = s1 + 256;

  wcvt<<<dim3(512), 256, 0, stream>>>(w_g, w_th, w_ph, w_w, wbh, wbl, wwh, wwl);
  zero_stats<<<dim3(1), 512, 0, stream>>>(s1);
  xt_cvt<<<dim3(64, 4, 8), 256, 0, stream>>>(x, xh);

  proj_fused<<<dim3(32, 8), 512, 0, stream>>>(xh, wbh, wbl, b_g, b_th, b_ph, thT, phT, gp);

  attn_mfma<<<dim3(32, 8), 512, 0, stream>>>(thT, phT, gp, yhb, ylb);

  conv_w_mfma<<<dim3(32, 8), 512, 0, stream>>>(yhb, ylb, wwh, wwl, b_w, wy, s1, s2);

  bn_res4<<<dim3(8192), 256, 0, stream>>>(wy, x, s1, s2, gam, bet, out);
}